// Round 3
// baseline (2664.884 us; speedup 1.0000x reference)
//
#include <hip/hip_runtime.h>

typedef unsigned int u32;
typedef unsigned long long u64;
typedef unsigned short u16;

// ---- problem constants ----
#define NB   16384
#define CIN  4096
#define LDIM 1024
#define KCB  8192
#define ODIM 128
#define NT16 (KCB / 16)     // 512 16-col groups per row
#define MARGIN 1e-3f        // prune margin in D space
#define CH   2048           // encoder row chunk (x-split buffer aliases smin)

using f32x4  = __attribute__((ext_vector_type(4))) float;
using short8 = __attribute__((ext_vector_type(8))) short;
using u16x8  = __attribute__((ext_vector_type(8))) u16;
using half8  = __attribute__((ext_vector_type(8))) _Float16;

__device__ __forceinline__ u64 packKey(float s, int idx) {
  u32 b = __float_as_uint(s);
  u32 k = (b & 0x80000000u) ? ~b : (b | 0x80000000u);
  return ((u64)k << 32) | (u32)idx;
}

__device__ __forceinline__ void gl_lds16(const void* g, void* l) {
  __builtin_amdgcn_global_load_lds((const __attribute__((address_space(1))) u32*)g,
                                   (__attribute__((address_space(3))) u32*)l, 16, 0, 0);
}

__device__ __forceinline__ u16 bf16rne(float f) {
  u32 u = __float_as_uint(f);
  u = u + 0x7fffu + ((u >> 16) & 1u);
  return (u16)(u >> 16);
}

// ---------------- f32 -> (hi fp16, lo fp16 scaled by 2^12), 8 elems/thread ----------------
__global__ __launch_bounds__(256)
void split_f16(const float* __restrict__ s, _Float16* __restrict__ hi,
               _Float16* __restrict__ lo)
{
  size_t i = ((size_t)blockIdx.x * 256 + threadIdx.x) * 8;
  _Float16 h8[8], l8[8];
#pragma unroll
  for (int j = 0; j < 8; j += 4) {
    float4 v = *(const float4*)(s + i + j);
    float vv[4] = { v.x, v.y, v.z, v.w };
#pragma unroll
    for (int q = 0; q < 4; q++) {
      float va = vv[q];
      _Float16 h = (fabsf(va) < 6.103515625e-5f) ? (_Float16)0.f : (_Float16)va;
      float r = (va - (float)h) * 4096.f;
      h8[j + q] = h;
      l8[j + q] = (_Float16)r;
    }
  }
  *(half8*)(hi + i) = *(half8*)h8;
  *(half8*)(lo + i) = *(half8*)l8;
}

// ---------------- f32 -> bf16 (RNE), 8 elems/thread ----------------
__global__ __launch_bounds__(256)
void f32_to_bf16(const float* __restrict__ s, u16* __restrict__ d)
{
  size_t i = ((size_t)blockIdx.x * 256 + threadIdx.x) * 8;
  float4 a = *(const float4*)(s + i);
  float4 b = *(const float4*)(s + i + 4);
  u16x8 o;
  o[0] = bf16rne(a.x); o[1] = bf16rne(a.y); o[2] = bf16rne(a.z); o[3] = bf16rne(a.w);
  o[4] = bf16rne(b.x); o[5] = bf16rne(b.y); o[6] = bf16rne(b.z); o[7] = bf16rne(b.w);
  *(u16x8*)(d + i) = o;
}

// ---------------- encoder: z = x @ W^T + b via fp16 2-way split, 3 MFMA products ----------------
__global__ __launch_bounds__(256)
void enc_split_gemm(const _Float16* __restrict__ xhi, const _Float16* __restrict__ xlo,
                    const _Float16* __restrict__ whi, const _Float16* __restrict__ wlo,
                    const float* __restrict__ bias, float* __restrict__ ze,
                    u16* __restrict__ zebf, int rowOff)
{
  __shared__ _Float16 Ah[128 * 32];
  __shared__ _Float16 Al[128 * 32];
  __shared__ _Float16 Bh[64 * 32];
  __shared__ _Float16 Bl[64 * 32];

  const int t = threadIdx.x;
  const int w = t >> 6, l = t & 63;
  const int rowBase = blockIdx.y * 128;   // within chunk
  const int colBase = blockIdx.x * 64;
  const int mB = (w >> 1) * 64, nB = (w & 1) * 32;
  const int q = l >> 4, n16 = l & 15;

  f32x4 hh[4][2] = {}, hl[4][2] = {}, lh[4][2] = {};

  const int sr = l >> 2;            // 0..15
  const int sk = (l & 3) * 8;
  const _Float16* gAh = xhi + (size_t)(rowBase + 32 * w + sr) * CIN + sk;
  const _Float16* gAl = xlo + (size_t)(rowBase + 32 * w + sr) * CIN + sk;
  const _Float16* gBh = whi + (size_t)(colBase + 16 * w + sr) * CIN + sk;
  const _Float16* gBl = wlo + (size_t)(colBase + 16 * w + sr) * CIN + sk;
  _Float16* lAh = Ah + 32 * w * 32;    // wave-uniform LDS bases
  _Float16* lAl = Al + 32 * w * 32;
  _Float16* lBh = Bh + 16 * w * 32;
  _Float16* lBl = Bl + 16 * w * 32;

  for (int kk = 0; kk < CIN; kk += 32) {
    gl_lds16(gAh + kk, lAh);
    gl_lds16(gAh + kk + 16 * CIN, lAh + 16 * 32);
    gl_lds16(gAl + kk, lAl);
    gl_lds16(gAl + kk + 16 * CIN, lAl + 16 * 32);
    gl_lds16(gBh + kk, lBh);
    gl_lds16(gBl + kk, lBl);
    __syncthreads();
    half8 ah[4], al[4], bh[2], bl[2];
#pragma unroll
    for (int ti = 0; ti < 4; ti++) {
      ah[ti] = *(const half8*)&Ah[(mB + ti * 16 + n16) * 32 + q * 8];
      al[ti] = *(const half8*)&Al[(mB + ti * 16 + n16) * 32 + q * 8];
    }
#pragma unroll
    for (int tj = 0; tj < 2; tj++) {
      bh[tj] = *(const half8*)&Bh[(nB + tj * 16 + n16) * 32 + q * 8];
      bl[tj] = *(const half8*)&Bl[(nB + tj * 16 + n16) * 32 + q * 8];
    }
    __syncthreads();   // frag reads done; next iter's loads may start during MFMA
#pragma unroll
    for (int ti = 0; ti < 4; ti++)
#pragma unroll
      for (int tj = 0; tj < 2; tj++) {
        hh[ti][tj] = __builtin_amdgcn_mfma_f32_16x16x32_f16(ah[ti], bh[tj], hh[ti][tj], 0, 0, 0);
        hl[ti][tj] = __builtin_amdgcn_mfma_f32_16x16x32_f16(ah[ti], bl[tj], hl[ti][tj], 0, 0, 0);
        lh[ti][tj] = __builtin_amdgcn_mfma_f32_16x16x32_f16(al[ti], bh[tj], lh[ti][tj], 0, 0, 0);
      }
  }

  const float S = 1.0f / 4096.0f;
#pragma unroll
  for (int tj = 0; tj < 2; tj++) {
    int c = colBase + nB + tj * 16 + n16;
    float b = bias[c];
#pragma unroll
    for (int ti = 0; ti < 4; ti++) {
      f32x4 z = hh[ti][tj] + S * (hl[ti][tj] + lh[ti][tj]);
      int m = rowOff + rowBase + mB + ti * 16 + q * 4;   // D row = quad*4+reg
#pragma unroll
      for (int r = 0; r < 4; r++) {
        float zv = z[r] + b;
        ze[(size_t)(m + r) * LDIM + c] = zv;
        zebf[(size_t)(m + r) * LDIM + c] = bf16rne(zv);
      }
    }
  }
}

// ---------------- prune GEMM: 256x256 tile, BK=64, 8 waves, 8-phase counted-vmcnt ----------------
// Rings: 4 slots per operand, each slot = 256 rows x 32 k bf16 (16 KiB); half index a = 2*tile + kslice.
// Stage calendar: prologue A0,B0,A1,B1,A2,B2; tile t phase j stages: j0:A(2t+3) j1:B(2t+3) j2:A(2t+4) j3:B(2t+4).
// vmcnt placed BEFORE the closing barrier of phases 1 and 3 (cross-wave completion via barrier):
//   end p1: need A/B(2t+1), 8 newer loads -> vmcnt(8)   [t==15: 0 newer -> vmcnt(0)]
//   end p3: need A/B(2t+2), 8 newer loads -> vmcnt(8)   [t==14: 4 newer -> vmcnt(4); t==15: none]
// LDS swizzle byte ^= ((row&3)<<4) both-sides (pre-swizzled global src, swizzled ds_read) -> 2-way residual.
#define VM8 asm volatile("s_waitcnt vmcnt(8)" ::: "memory")
#define VM4 asm volatile("s_waitcnt vmcnt(4)" ::: "memory")
#define VM0 asm volatile("s_waitcnt vmcnt(0)" ::: "memory")

__global__ __launch_bounds__(512, 2)
void gemm_bf16_min8(const u16* __restrict__ A, const u16* __restrict__ B,
                    float* __restrict__ smin)
{
  __shared__ u16 ringA[4][8192];
  __shared__ u16 ringB[4][8192];

  const int tid = threadIdx.x;
  const int w = tid >> 6, l = tid & 63;
  const int wr = w >> 2, wc = w & 3;          // 2 x 4 wave grid; wave C = 128 x 64
  const int q = l >> 4, n16 = l & 15;
  const int qx = (q ^ (n16 & 3)) << 4;        // swizzled 16B slot within 64B row

  // XCD-aware bijective block swizzle (2048 % 8 == 0)
  const int bid = blockIdx.x;
  const int wgid = (bid & 7) * 256 + (bid >> 3);
  const int bCol = wgid & 31, bRow = wgid >> 5;

  // staging: linear LDS fill at o, pre-swizzled global source at swz(o)
  const int o0 = tid * 16, o1 = 8192 + tid * 16;
  const int s0 = o0 ^ (((o0 >> 6) & 3) << 4);
  const int s1 = o1 ^ (((o1 >> 6) & 3) << 4);
  const u16* gA0 = A + (size_t)((bRow << 8) + (s0 >> 6)) * LDIM + ((s0 & 63) >> 1);
  const u16* gA1 = A + (size_t)((bRow << 8) + (s1 >> 6)) * LDIM + ((s1 & 63) >> 1);
  const u16* gB0 = B + (size_t)((bCol << 8) + (s0 >> 6)) * LDIM + ((s0 & 63) >> 1);
  const u16* gB1 = B + (size_t)((bCol << 8) + (s1 >> 6)) * LDIM + ((s1 & 63) >> 1);

  auto stA = [&](int a) {
    if (a < 32) {
      char* d = (char*)ringA[a & 3];
      gl_lds16(gA0 + a * 32, d + o0);
      gl_lds16(gA1 + a * 32, d + o1);
    }
  };
  auto stB = [&](int a) {
    if (a < 32) {
      char* d = (char*)ringB[a & 3];
      gl_lds16(gB0 + a * 32, d + o0);
      gl_lds16(gB1 + a * 32, d + o1);
    }
  };

  f32x4 acc[8][4] = {};

  // prologue: 6 half-tiles in flight; A0,B0 complete after vmcnt(8)+barrier
  stA(0); stB(0); stA(1); stB(1); stA(2); stB(2);
  VM8;
  __builtin_amdgcn_s_barrier();

  const int arow = wr * 128 + n16;
  const int brow = wc * 64 + n16;

#pragma unroll 1
  for (int t = 0; t < 16; ++t) {
#pragma unroll
    for (int j = 0; j < 4; ++j) {
      // frag ds_reads (slot of kslice j>>1); 8 x ds_read_b128
      const char* pa = (const char*)ringA[(2 * t + (j >> 1)) & 3]
                       + (size_t)(arow + (j & 1) * 64) * 64 + qx;
      const char* pb = (const char*)ringB[(2 * t + (j >> 1)) & 3]
                       + (size_t)brow * 64 + qx;
      short8 af[4], bf[4];
#pragma unroll
      for (int fi = 0; fi < 4; fi++)
        af[fi] = *(const short8*)(pa + fi * (16 * 64));
#pragma unroll
      for (int fj = 0; fj < 4; fj++)
        bf[fj] = *(const short8*)(pb + fj * (16 * 64));

      // stage one half-tile (slot freed by the previous phase's barrier)
      if (j == 0)      stA(2 * t + 3);
      else if (j == 1) stB(2 * t + 3);
      else if (j == 2) stA(2 * t + 4);
      else             stB(2 * t + 4);

      __builtin_amdgcn_s_barrier();
      asm volatile("s_waitcnt lgkmcnt(0)" ::: "memory");
      __builtin_amdgcn_sched_barrier(0);

      __builtin_amdgcn_s_setprio(1);
#pragma unroll
      for (int fi = 0; fi < 4; fi++)
#pragma unroll
        for (int fj = 0; fj < 4; fj++)
          acc[(j & 1) * 4 + fi][fj] =
            __builtin_amdgcn_mfma_f32_16x16x32_bf16(af[fi], bf[fj],
                                                    acc[(j & 1) * 4 + fi][fj], 0, 0, 0);
      __builtin_amdgcn_s_setprio(0);

      // counted vmcnt BEFORE the closing barrier (never drain to 0 mid-loop)
      if (j == 1) { if (t < 15) { VM8; } else { VM0; } }
      if (j == 3) { if (t < 14) { VM8; } else if (t == 14) { VM4; } }
      __builtin_amdgcn_s_barrier();
    }
  }

  // epilogue: per-fragment min over 16 cols (one col-group per fragment)
  const int g0 = bCol * 16 + wc * 4;
  const int m0 = bRow * 256 + wr * 128 + q * 4;
#pragma unroll
  for (int mi = 0; mi < 8; mi++)
#pragma unroll
    for (int fj = 0; fj < 4; fj++) {
      f32x4 v = acc[mi][fj];
#pragma unroll
      for (int off = 1; off < 16; off <<= 1) {
        v.x = fmaxf(v.x, __shfl_xor(v.x, off));
        v.y = fmaxf(v.y, __shfl_xor(v.y, off));
        v.z = fmaxf(v.z, __shfl_xor(v.z, off));
        v.w = fmaxf(v.w, __shfl_xor(v.w, off));
      }
      if (n16 == 0) {
        float* p = smin + (size_t)(m0 + mi * 16) * NT16 + g0 + fj;
        p[0 * NT16] = -2.f * v.x;
        p[1 * NT16] = -2.f * v.y;
        p[2 * NT16] = -2.f * v.z;
        p[3 * NT16] = -2.f * v.w;
      }
    }
}

// ---------------- dst[r] = ||src[r]||^2 (width 1024), one wave per row ----------------
__global__ __launch_bounds__(256)
void sqnorm_kernel(const float* __restrict__ src, float* __restrict__ dst)
{
  int row  = blockIdx.x * 4 + (threadIdx.x >> 6);
  int lane = threadIdx.x & 63;
  const float* p = src + (size_t)row * LDIM + lane * 4;
  float s = 0.f;
#pragma unroll
  for (int j = 0; j < 4; j++) {
    float4 v = *(const float4*)(p + j * 256);
    s += v.x * v.x + v.y * v.y + v.z * v.z + v.w * v.w;
  }
#pragma unroll
  for (int off = 32; off; off >>= 1) s += __shfl_down(s, off, 64);
  if (lane == 0) dst[row] = s;
}

// ---------------- phase A: qualify groups, emit (row,group) pairs to queue ----------------
__global__ __launch_bounds__(256)
void qualify_kernel(const float* __restrict__ smin, u32* __restrict__ queue,
                    u32* __restrict__ qcount)
{
  const int t = threadIdx.x;
  const int row = blockIdx.x * 4 + (t >> 6);
  const int l = t & 63;
  const float* sm = smin + (size_t)row * NT16;

  float v[8]; float gmin = 1e30f;
#pragma unroll
  for (int s = 0; s < 8; s++) { v[s] = sm[s * 64 + l]; gmin = fminf(gmin, v[s]); }
#pragma unroll
  for (int off = 1; off < 64; off <<= 1) gmin = fminf(gmin, __shfl_xor(gmin, off));
  const float thr = gmin + MARGIN;

#pragma unroll
  for (int s = 0; s < 8; s++) {
    bool hit = (v[s] <= thr);
    u64 mask = __ballot(hit);
    int nb = __popcll(mask);
    if (nb) {
      u32 base = 0;
      if (l == 0) base = atomicAdd(qcount, (u32)nb);
      base = __shfl(base, 0, 64);
      if (hit) {
        int rank = __popcll(mask & ((1ull << l) - 1ull));
        queue[base + rank] = ((u32)row << 9) | (u32)(s * 64 + l);
      }
    }
  }
}

// ---------------- phase B: exact fp32 rescore, one wave per (row,group) pair ----------------
__global__ __launch_bounds__(256)
void rescore_pairs(const u32* __restrict__ queue, const u32* __restrict__ qcount,
                   const float* __restrict__ ze, const float* __restrict__ zz,
                   const float* __restrict__ cb, u64* __restrict__ packed)
{
  const int l = threadIdx.x & 63;
  const u32 nw = gridDim.x * 4;
  const u32 wid = blockIdx.x * 4 + (threadIdx.x >> 6);
  const u32 n = *qcount;

  for (u32 i = wid; i < n; i += nw) {
    u32 p = queue[i];
    u32 row = p >> 9, g = p & 511u;
    const float* z = ze + (size_t)row * LDIM;
    f32x4 zf[4];
#pragma unroll
    for (int j = 0; j < 4; j++)
      zf[j] = *(const f32x4*)(z + j * 256 + l * 4);
    const float zzr = zz[row];
    u64 best = ~0ull;

#pragma unroll 1
    for (int c4 = 0; c4 < 4; c4++) {
      const int colBase = (int)g * 16 + c4 * 4;
      const float* cp = cb + (size_t)colBase * LDIM;
      f32x4 e0[4], e1[4], e2[4], e3[4];
#pragma unroll
      for (int j = 0; j < 4; j++) {
        e0[j] = *(const f32x4*)(cp + 0 * LDIM + j * 256 + l * 4);
        e1[j] = *(const f32x4*)(cp + 1 * LDIM + j * 256 + l * 4);
        e2[j] = *(const f32x4*)(cp + 2 * LDIM + j * 256 + l * 4);
        e3[j] = *(const f32x4*)(cp + 3 * LDIM + j * 256 + l * 4);
      }
      float d0 = 0.f, d1 = 0.f, d2 = 0.f, d3 = 0.f;
#pragma unroll
      for (int j = 0; j < 4; j++)
#pragma unroll
        for (int qq = 0; qq < 4; qq++) {
          float zv = zf[j][qq];
          d0 = fmaf(zv, e0[j][qq], d0);
          d1 = fmaf(zv, e1[j][qq], d1);
          d2 = fmaf(zv, e2[j][qq], d2);
          d3 = fmaf(zv, e3[j][qq], d3);
        }
#pragma unroll
      for (int off = 1; off < 64; off <<= 1) {
        d0 += __shfl_xor(d0, off);
        d1 += __shfl_xor(d1, off);
        d2 += __shfl_xor(d2, off);
        d3 += __shfl_xor(d3, off);
      }
      u64 k;
      k = packKey(zzr - 2.f * d0, colBase + 0); if (k < best) best = k;
      k = packKey(zzr - 2.f * d1, colBase + 1); if (k < best) best = k;
      k = packKey(zzr - 2.f * d2, colBase + 2); if (k < best) best = k;
      k = packKey(zzr - 2.f * d3, colBase + 3); if (k < best) best = k;
    }
    if (l == 0) atomicMin(&packed[row], best);
  }
}

// ---------------- P = cb @ W_cls^T + b_cls; block = 32 cb-rows x 128 cols ----------------
__global__ __launch_bounds__(256)
void p_kernel(const float* __restrict__ cb, const float* __restrict__ W,
              const float* __restrict__ b, float* __restrict__ P)
{
  __shared__ float Ws[128][33];
  __shared__ float Cs[32][33];
  const int t = threadIdx.x;
  const int r = t >> 3, og = t & 7;
  const int kRow = blockIdx.x * 32;

  float acc[16];
#pragma unroll
  for (int j = 0; j < 16; j++) acc[j] = 0.f;

  for (int kt = 0; kt < LDIM; kt += 32) {
    __syncthreads();
    {
      int o = t >> 1, half = t & 1;
      const float* wp = W + (size_t)o * LDIM + kt + half * 16;
#pragma unroll
      for (int j = 0; j < 4; j++) {
        float4 vv = *(const float4*)(wp + j * 4);
        Ws[o][half * 16 + j * 4 + 0] = vv.x;
        Ws[o][half * 16 + j * 4 + 1] = vv.y;
        Ws[o][half * 16 + j * 4 + 2] = vv.z;
        Ws[o][half * 16 + j * 4 + 3] = vv.w;
      }
      int cr = t >> 3, cc = (t & 7) * 4;
      float4 cv = *(const float4*)(cb + (size_t)(kRow + cr) * LDIM + kt + cc);
      Cs[cr][cc + 0] = cv.x; Cs[cr][cc + 1] = cv.y;
      Cs[cr][cc + 2] = cv.z; Cs[cr][cc + 3] = cv.w;
    }
    __syncthreads();
#pragma unroll
    for (int lt = 0; lt < 32; lt++) {
      float cv = Cs[r][lt];
#pragma unroll
      for (int j = 0; j < 16; j++)
        acc[j] = fmaf(cv, Ws[og + 8 * j][lt], acc[j]);
    }
  }
  float* pp = P + (size_t)(kRow + r) * ODIM;
#pragma unroll
  for (int j = 0; j < 16; j++)
    pp[og + 8 * j] = acc[j] + b[og + 8 * j];
}

// ---------------- finalize: idx, loss partial, softmax(P[idx]) ----------------
__global__ __launch_bounds__(256)
void finalize_kernel(const u64* __restrict__ packed, const float* __restrict__ P,
                     float* __restrict__ out, float* __restrict__ lossAcc)
{
  __shared__ float blockLoss;
  const int t = threadIdx.x;
  if (t == 0) blockLoss = 0.f;
  const int g = t >> 5, l = t & 31;
  const int row = blockIdx.x * 8 + g;

  u64 pk = packed[row];
  int idx = (int)(u32)(pk & 0xFFFFFFFFull);
  u32 ku = (u32)(pk >> 32);
  u32 sb = (ku & 0x80000000u) ? (ku & 0x7fffffffu) : ~ku;
  float dmin = __uint_as_float(sb);

  __syncthreads();
  if (l == 0) {
    out[(size_t)NB * ODIM + 1 + row] = (float)idx;
    atomicAdd(&blockLoss, dmin);
  }

  float4 p4 = *(const float4*)(P + (size_t)idx * ODIM + l * 4);
  float m = fmaxf(fmaxf(p4.x, p4.y), fmaxf(p4.z, p4.w));
#pragma unroll
  for (int off = 1; off < 32; off <<= 1) m = fmaxf(m, __shfl_xor(m, off, 32));
  float4 ex = { __expf(p4.x - m), __expf(p4.y - m), __expf(p4.z - m), __expf(p4.w - m) };
  float s = ex.x + ex.y + ex.z + ex.w;
#pragma unroll
  for (int off = 1; off < 32; off <<= 1) s += __shfl_xor(s, off, 32);
  float inv = 1.f / s;
  float4 o4 = { ex.x * inv, ex.y * inv, ex.z * inv, ex.w * inv };
  *(float4*)(out + (size_t)row * ODIM + l * 4) = o4;

  __syncthreads();
  if (t == 0) atomicAdd(lossAcc, blockLoss);
}

__global__ void final_loss(const float* __restrict__ lossAcc, float* __restrict__ out)
{
  out[(size_t)NB * ODIM] = 1.25f * lossAcc[0] / (float)((size_t)NB * LDIM);
}

extern "C" void kernel_launch(void* const* d_in, const int* in_sizes, int n_in,
                              void* d_out, int out_size, void* d_ws, size_t ws_size,
                              hipStream_t stream)
{
  const float* x     = (const float*)d_in[0];
  const float* W_enc = (const float*)d_in[1];
  const float* b_enc = (const float*)d_in[2];
  const float* cb    = (const float*)d_in[3];
  const float* W_cls = (const float*)d_in[4];
  const float* b_cls = (const float*)d_in[5];
  float* out = (float*)d_out;

  char* ws = (char*)d_ws;
  size_t off = 0;
  float* ze      = (float*)(ws + off); off += (size_t)NB * LDIM * 4;      // 64 MiB
  float* zz      = (float*)(ws + off); off += (size_t)NB * 4;             // 64 KiB
  u64*   packed  = (u64*)  (ws + off); off += (size_t)NB * 8;             // 128 KiB
  float* lossAcc = (float*)(ws + off); off += 256;                        // loss + qcount
  float* P       = (float*)(ws + off); off += (size_t)KCB * ODIM * 4;     // 4 MiB
  u16*   zebf    = (u16*)  (ws + off); off += (size_t)NB * LDIM * 2;      // 32 MiB
  char*  cbbfR   = (ws + off);         off += (size_t)KCB * LDIM * 2;     // 16 MiB (alias: W splits)
  char*  sminR   = (ws + off);         off += (size_t)NB * NT16 * 4;      // 32 MiB (alias: x-split chunk)

  // aliases (encoder phase): W splits live in cbbf region; x-chunk splits in smin region
  _Float16* whi = (_Float16*)cbbfR;                                  // 8 MiB
  _Float16* wlo = (_Float16*)(cbbfR + (size_t)LDIM * CIN * 2);       // 8 MiB
  _Float16* xhi = (_Float16*)sminR;                                  // 16 MiB
  _Float16* xlo = (_Float16*)(sminR + (size_t)CH * CIN * 2);         // 16 MiB
  u16*   cbbf = (u16*)cbbfR;
  float* smin = (float*)sminR;
  // candidate queue aliases zebf (dead after gemm); qcount in lossAcc block
  u32*   queue  = (u32*)zebf;
  u32*   qcount = (u32*)((char*)lossAcc + 64);

  hipMemsetAsync(packed, 0xFF, (size_t)NB * 8, stream);
  hipMemsetAsync(lossAcc, 0, 256, stream);

  // W_enc -> fp16 hi/lo'
  split_f16<<<(LDIM * CIN) / 2048, 256, 0, stream>>>(W_enc, whi, wlo);

  // chunked encoder: x-chunk -> fp16 hi/lo' (in smin region), then split-GEMM
  for (int c = 0; c < NB / CH; c++) {
    split_f16<<<(CH * CIN) / 2048, 256, 0, stream>>>(x + (size_t)c * CH * CIN, xhi, xlo);
    enc_split_gemm<<<dim3(LDIM / 64, CH / 128), 256, 0, stream>>>(
        xhi, xlo, whi, wlo, b_enc, ze, zebf, c * CH);
  }

  sqnorm_kernel<<<NB / 4, 256, 0, stream>>>(ze, zz);

  // cb -> bf16 (overwrites W splits; encoder done by stream order)
  f32_to_bf16<<<(KCB * LDIM) / 2048, 256, 0, stream>>>(cb, cbbf);

  // prune GEMM: 256^2 8-phase (T1+T2+T3/T4+T5)
  gemm_bf16_min8<<<(NB / 256) * (KCB / 256), 512, 0, stream>>>(zebf, cbbf, smin);

  // two-phase rescore: qualify -> pair queue (in dead zebf) -> parallel exact rescore
  qualify_kernel<<<NB / 4, 256, 0, stream>>>(smin, queue, qcount);
  rescore_pairs<<<2048, 256, 0, stream>>>(queue, qcount, ze, zz, cb, packed);

  p_kernel<<<KCB / 32, 256, 0, stream>>>(cb, W_cls, b_cls, P);

  finalize_kernel<<<NB / 8, 256, 0, stream>>>(packed, P, out, lossAcc);
  final_loss<<<1, 1, 0, stream>>>(lossAcc, out);
}

// Round 9
// 1987.896 us; speedup vs baseline: 1.3406x; 1.3406x over previous
//
#include <hip/hip_runtime.h>

typedef unsigned int u32;
typedef unsigned long long u64;
typedef unsigned short u16;

// ---- problem constants ----
#define NB   16384
#define CIN  4096
#define LDIM 1024
#define KCB  8192
#define ODIM 128
#define NT16 (KCB / 16)     // 512 16-col groups per row
#define MARGIN 1e-3f        // prune margin in D space

using f32x4  = __attribute__((ext_vector_type(4))) float;
using short8 = __attribute__((ext_vector_type(8))) short;
using u16x8  = __attribute__((ext_vector_type(8))) u16;
using half8  = __attribute__((ext_vector_type(8))) _Float16;

__device__ __forceinline__ u64 packKey(float s, int idx) {
  u32 b = __float_as_uint(s);
  u32 k = (b & 0x80000000u) ? ~b : (b | 0x80000000u);
  return ((u64)k << 32) | (u32)idx;
}

__device__ __forceinline__ void gl_lds16(const void* g, void* l) {
  __builtin_amdgcn_global_load_lds((const __attribute__((address_space(1))) u32*)g,
                                   (__attribute__((address_space(3))) u32*)l, 16, 0, 0);
}

__device__ __forceinline__ u16 bf16rne(float f) {
  u32 u = __float_as_uint(f);
  u = u + 0x7fffu + ((u >> 16) & 1u);
  return (u16)(u >> 16);
}

// exact same split sequence as the old split_f16 kernel (numerics preserved)
__device__ __forceinline__ void cvt_hl(float va, _Float16& h, _Float16& lo) {
  _Float16 hh = (fabsf(va) < 6.103515625e-5f) ? (_Float16)0.f : (_Float16)va;
  h = hh;
  lo = (_Float16)((va - (float)hh) * 4096.f);
}

// ---------------- f32 -> (hi fp16, lo fp16 scaled by 2^12), 8 elems/thread ----------------
// (still used once, for W_enc)
__global__ __launch_bounds__(256)
void split_f16(const float* __restrict__ s, _Float16* __restrict__ hi,
               _Float16* __restrict__ lo)
{
  size_t i = ((size_t)blockIdx.x * 256 + threadIdx.x) * 8;
  _Float16 h8[8], l8[8];
#pragma unroll
  for (int j = 0; j < 8; j += 4) {
    float4 v = *(const float4*)(s + i + j);
    float vv[4] = { v.x, v.y, v.z, v.w };
#pragma unroll
    for (int q = 0; q < 4; q++)
      cvt_hl(vv[q], h8[j + q], l8[j + q]);
  }
  *(half8*)(hi + i) = *(half8*)h8;
  *(half8*)(lo + i) = *(half8*)l8;
}

// ---------------- f32 -> bf16 (RNE), 8 elems/thread ----------------
__global__ __launch_bounds__(256)
void f32_to_bf16(const float* __restrict__ s, u16* __restrict__ d)
{
  size_t i = ((size_t)blockIdx.x * 256 + threadIdx.x) * 8;
  float4 a = *(const float4*)(s + i);
  float4 b = *(const float4*)(s + i + 4);
  u16x8 o;
  o[0] = bf16rne(a.x); o[1] = bf16rne(a.y); o[2] = bf16rne(a.z); o[3] = bf16rne(a.w);
  o[4] = bf16rne(b.x); o[5] = bf16rne(b.y); o[6] = bf16rne(b.z); o[7] = bf16rne(b.w);
  *(u16x8*)(d + i) = o;
}

// ---------------- encoder: z = x @ W^T + b, x-split FUSED in-kernel ----------------
// Block 128 rows x 64 cols, 4 waves (2x2 of 64x32). BK=32.
// A: load x f32 -> cvt to hi/lo in regs -> ds_write (contiguous, conflict-free).
// B: pre-split whi/wlo staged via global_load_lds w16.
// z = hh + 2^-12*(hl + lh); epilogue writes ze fp32 AND zebf bf16.
// Single launch over all 16384 rows: 2048 blocks, 24KB LDS -> 2+ blocks/CU.
__global__ __launch_bounds__(256, 2)
void enc_fused_gemm(const float* __restrict__ x,
                    const _Float16* __restrict__ whi, const _Float16* __restrict__ wlo,
                    const float* __restrict__ bias, float* __restrict__ ze,
                    u16* __restrict__ zebf)
{
  __shared__ _Float16 Ah[128 * 32];
  __shared__ _Float16 Al[128 * 32];
  __shared__ _Float16 Bh[64 * 32];
  __shared__ _Float16 Bl[64 * 32];

  const int t = threadIdx.x;
  const int w = t >> 6, l = t & 63;
  const int rowBase = blockIdx.y * 128;
  const int colBase = blockIdx.x * 64;
  const int mB = (w >> 1) * 64, nB = (w & 1) * 32;
  const int q = l >> 4, n16 = l & 15;

  f32x4 hh[4][2] = {}, hl[4][2] = {}, lh[4][2] = {};

  // A staging: thread handles rows {t>>2, 64+(t>>2)}, k-quarter (t&3)*8 (8 f32 = 32B contig)
  const int ar = t >> 2;            // 0..63
  const int ak = (t & 3) * 8;       // 0,8,16,24
  const float* gx0 = x + (size_t)(rowBase + ar) * CIN + ak;
  const float* gx1 = x + (size_t)(rowBase + 64 + ar) * CIN + ak;

  // W staging (async global->LDS), same as before
  const int sr = l >> 2;            // 0..15
  const int sk = (l & 3) * 8;
  const _Float16* gBh = whi + (size_t)(colBase + 16 * w + sr) * CIN + sk;
  const _Float16* gBl = wlo + (size_t)(colBase + 16 * w + sr) * CIN + sk;
  _Float16* lBh = Bh + 16 * w * 32;
  _Float16* lBl = Bl + 16 * w * 32;

  for (int kk = 0; kk < CIN; kk += 32) {
    gl_lds16(gBh + kk, lBh);
    gl_lds16(gBl + kk, lBl);

    // x: 2 rows x 8 elems, convert, write h/l (lane addrs contiguous -> b128 floor)
    float4 v0a = *(const float4*)(gx0 + kk);
    float4 v0b = *(const float4*)(gx0 + kk + 4);
    float4 v1a = *(const float4*)(gx1 + kk);
    float4 v1b = *(const float4*)(gx1 + kk + 4);
    _Float16 h0[8], l0[8], h1[8], l1[8];
    float u0[8] = { v0a.x, v0a.y, v0a.z, v0a.w, v0b.x, v0b.y, v0b.z, v0b.w };
    float u1[8] = { v1a.x, v1a.y, v1a.z, v1a.w, v1b.x, v1b.y, v1b.z, v1b.w };
#pragma unroll
    for (int j = 0; j < 8; j++) {
      cvt_hl(u0[j], h0[j], l0[j]);
      cvt_hl(u1[j], h1[j], l1[j]);
    }
    *(half8*)&Ah[ar * 32 + ak]        = *(half8*)h0;
    *(half8*)&Al[ar * 32 + ak]        = *(half8*)l0;
    *(half8*)&Ah[(64 + ar) * 32 + ak] = *(half8*)h1;
    *(half8*)&Al[(64 + ar) * 32 + ak] = *(half8*)l1;

    __syncthreads();
    half8 ah[4], al[4], bh[2], bl[2];
#pragma unroll
    for (int ti = 0; ti < 4; ti++) {
      ah[ti] = *(const half8*)&Ah[(mB + ti * 16 + n16) * 32 + q * 8];
      al[ti] = *(const half8*)&Al[(mB + ti * 16 + n16) * 32 + q * 8];
    }
#pragma unroll
    for (int tj = 0; tj < 2; tj++) {
      bh[tj] = *(const half8*)&Bh[(nB + tj * 16 + n16) * 32 + q * 8];
      bl[tj] = *(const half8*)&Bl[(nB + tj * 16 + n16) * 32 + q * 8];
    }
    __syncthreads();   // frag reads done; next iter's writes may start during MFMA
#pragma unroll
    for (int ti = 0; ti < 4; ti++)
#pragma unroll
      for (int tj = 0; tj < 2; tj++) {
        hh[ti][tj] = __builtin_amdgcn_mfma_f32_16x16x32_f16(ah[ti], bh[tj], hh[ti][tj], 0, 0, 0);
        hl[ti][tj] = __builtin_amdgcn_mfma_f32_16x16x32_f16(ah[ti], bl[tj], hl[ti][tj], 0, 0, 0);
        lh[ti][tj] = __builtin_amdgcn_mfma_f32_16x16x32_f16(al[ti], bh[tj], lh[ti][tj], 0, 0, 0);
      }
  }

  const float S = 1.0f / 4096.0f;
#pragma unroll
  for (int tj = 0; tj < 2; tj++) {
    int c = colBase + nB + tj * 16 + n16;
    float b = bias[c];
#pragma unroll
    for (int ti = 0; ti < 4; ti++) {
      f32x4 z = hh[ti][tj] + S * (hl[ti][tj] + lh[ti][tj]);
      int m = rowBase + mB + ti * 16 + q * 4;   // D row = quad*4+reg
#pragma unroll
      for (int r = 0; r < 4; r++) {
        float zv = z[r] + b;
        ze[(size_t)(m + r) * LDIM + c] = zv;
        zebf[(size_t)(m + r) * LDIM + c] = bf16rne(zv);
      }
    }
  }
}

// ---------------- bf16 MFMA GEMM, per-(row,16colgroup) min of -2*dot ----------------
__global__ __launch_bounds__(256, 3)
void gemm_bf16_min(const u16* __restrict__ A, const u16* __restrict__ B,
                   float* __restrict__ smin)
{
  __shared__ u16 As[128 * 32];
  __shared__ u16 Bs[128 * 32];
  const int t = threadIdx.x;
  const int w = t >> 6, l = t & 63;
  const int rowBase = blockIdx.y * 128, colBase = blockIdx.x * 128;
  const int mB = (w >> 1) * 64, nB = (w & 1) * 64;
  const int q = l >> 4, n16 = l & 15;

  f32x4 acc[4][4] = {};

  const int sr = 32 * w + (l >> 2);
  const int sk = (l & 3) * 8;
  const u16* gA = A + (size_t)(rowBase + sr) * LDIM + sk;
  const u16* gB = B + (size_t)(colBase + sr) * LDIM + sk;
  u16* lA = As + 32 * w * 32;
  u16* lB = Bs + 32 * w * 32;

  for (int kk = 0; kk < LDIM; kk += 32) {
    gl_lds16(gA + kk, lA);
    gl_lds16(gA + kk + 16 * LDIM, lA + 16 * 32);
    gl_lds16(gB + kk, lB);
    gl_lds16(gB + kk + 16 * LDIM, lB + 16 * 32);
    __syncthreads();
    short8 af[4], bf[4];
#pragma unroll
    for (int ti = 0; ti < 4; ti++)
      af[ti] = *(const short8*)&As[(mB + ti * 16 + n16) * 32 + q * 8];
#pragma unroll
    for (int tj = 0; tj < 4; tj++)
      bf[tj] = *(const short8*)&Bs[(nB + tj * 16 + n16) * 32 + q * 8];
#pragma unroll
    for (int ti = 0; ti < 4; ti++)
#pragma unroll
      for (int tj = 0; tj < 4; tj++)
        acc[ti][tj] = __builtin_amdgcn_mfma_f32_16x16x32_bf16(af[ti], bf[tj], acc[ti][tj], 0, 0, 0);
    __syncthreads();
  }

  const int g0 = blockIdx.x * 8 + (w & 1) * 4;
#pragma unroll
  for (int ti = 0; ti < 4; ti++)
#pragma unroll
    for (int tj = 0; tj < 4; tj++) {
      f32x4 v = acc[ti][tj];
#pragma unroll
      for (int off = 1; off < 16; off <<= 1) {
        v.x = fmaxf(v.x, __shfl_xor(v.x, off));
        v.y = fmaxf(v.y, __shfl_xor(v.y, off));
        v.z = fmaxf(v.z, __shfl_xor(v.z, off));
        v.w = fmaxf(v.w, __shfl_xor(v.w, off));
      }
      if (n16 == 0) {
        int m = rowBase + mB + ti * 16 + q * 4;
        float* p = smin + (size_t)m * NT16 + g0 + tj;
        p[0 * NT16] = -2.f * v.x;
        p[1 * NT16] = -2.f * v.y;
        p[2 * NT16] = -2.f * v.z;
        p[3 * NT16] = -2.f * v.w;
      }
    }
}

// ---------------- dst[r] = ||src[r]||^2 (width 1024), one wave per row ----------------
__global__ __launch_bounds__(256)
void sqnorm_kernel(const float* __restrict__ src, float* __restrict__ dst)
{
  int row  = blockIdx.x * 4 + (threadIdx.x >> 6);
  int lane = threadIdx.x & 63;
  const float* p = src + (size_t)row * LDIM + lane * 4;
  float s = 0.f;
#pragma unroll
  for (int j = 0; j < 4; j++) {
    float4 v = *(const float4*)(p + j * 256);
    s += v.x * v.x + v.y * v.y + v.z * v.z + v.w * v.w;
  }
#pragma unroll
  for (int off = 32; off; off >>= 1) s += __shfl_down(s, off, 64);
  if (lane == 0) dst[row] = s;
}

// ---------------- phase A: qualify groups, emit (row,group) pairs to queue ----------------
__global__ __launch_bounds__(256)
void qualify_kernel(const float* __restrict__ smin, u32* __restrict__ queue,
                    u32* __restrict__ qcount)
{
  const int t = threadIdx.x;
  const int row = blockIdx.x * 4 + (t >> 6);
  const int l = t & 63;
  const float* sm = smin + (size_t)row * NT16;

  float v[8]; float gmin = 1e30f;
#pragma unroll
  for (int s = 0; s < 8; s++) { v[s] = sm[s * 64 + l]; gmin = fminf(gmin, v[s]); }
#pragma unroll
  for (int off = 1; off < 64; off <<= 1) gmin = fminf(gmin, __shfl_xor(gmin, off));
  const float thr = gmin + MARGIN;

#pragma unroll
  for (int s = 0; s < 8; s++) {
    bool hit = (v[s] <= thr);
    u64 mask = __ballot(hit);
    int nb = __popcll(mask);
    if (nb) {
      u32 base = 0;
      if (l == 0) base = atomicAdd(qcount, (u32)nb);
      base = __shfl(base, 0, 64);
      if (hit) {
        int rank = __popcll(mask & ((1ull << l) - 1ull));
        queue[base + rank] = ((u32)row << 9) | (u32)(s * 64 + l);
      }
    }
  }
}

// ---------------- phase B: exact fp32 rescore, one wave per (row,group) pair ----------------
__global__ __launch_bounds__(256)
void rescore_pairs(const u32* __restrict__ queue, const u32* __restrict__ qcount,
                   const float* __restrict__ ze, const float* __restrict__ zz,
                   const float* __restrict__ cb, u64* __restrict__ packed)
{
  const int l = threadIdx.x & 63;
  const u32 nw = gridDim.x * 4;
  const u32 wid = blockIdx.x * 4 + (threadIdx.x >> 6);
  const u32 n = *qcount;

  for (u32 i = wid; i < n; i += nw) {
    u32 p = queue[i];
    u32 row = p >> 9, g = p & 511u;
    const float* z = ze + (size_t)row * LDIM;
    f32x4 zf[4];
#pragma unroll
    for (int j = 0; j < 4; j++)
      zf[j] = *(const f32x4*)(z + j * 256 + l * 4);
    const float zzr = zz[row];
    u64 best = ~0ull;

#pragma unroll 1
    for (int c4 = 0; c4 < 4; c4++) {
      const int colBase = (int)g * 16 + c4 * 4;
      const float* cp = cb + (size_t)colBase * LDIM;
      f32x4 e0[4], e1[4], e2[4], e3[4];
#pragma unroll
      for (int j = 0; j < 4; j++) {
        e0[j] = *(const f32x4*)(cp + 0 * LDIM + j * 256 + l * 4);
        e1[j] = *(const f32x4*)(cp + 1 * LDIM + j * 256 + l * 4);
        e2[j] = *(const f32x4*)(cp + 2 * LDIM + j * 256 + l * 4);
        e3[j] = *(const f32x4*)(cp + 3 * LDIM + j * 256 + l * 4);
      }
      float d0 = 0.f, d1 = 0.f, d2 = 0.f, d3 = 0.f;
#pragma unroll
      for (int j = 0; j < 4; j++)
#pragma unroll
        for (int qq = 0; qq < 4; qq++) {
          float zv = zf[j][qq];
          d0 = fmaf(zv, e0[j][qq], d0);
          d1 = fmaf(zv, e1[j][qq], d1);
          d2 = fmaf(zv, e2[j][qq], d2);
          d3 = fmaf(zv, e3[j][qq], d3);
        }
#pragma unroll
      for (int off = 1; off < 64; off <<= 1) {
        d0 += __shfl_xor(d0, off);
        d1 += __shfl_xor(d1, off);
        d2 += __shfl_xor(d2, off);
        d3 += __shfl_xor(d3, off);
      }
      u64 k;
      k = packKey(zzr - 2.f * d0, colBase + 0); if (k < best) best = k;
      k = packKey(zzr - 2.f * d1, colBase + 1); if (k < best) best = k;
      k = packKey(zzr - 2.f * d2, colBase + 2); if (k < best) best = k;
      k = packKey(zzr - 2.f * d3, colBase + 3); if (k < best) best = k;
    }
    if (l == 0) atomicMin(&packed[row], best);
  }
}

// ---------------- P = cb @ W_cls^T + b_cls; block = 32 cb-rows x 128 cols ----------------
__global__ __launch_bounds__(256)
void p_kernel(const float* __restrict__ cb, const float* __restrict__ W,
              const float* __restrict__ b, float* __restrict__ P)
{
  __shared__ float Ws[128][33];
  __shared__ float Cs[32][33];
  const int t = threadIdx.x;
  const int r = t >> 3, og = t & 7;
  const int kRow = blockIdx.x * 32;

  float acc[16];
#pragma unroll
  for (int j = 0; j < 16; j++) acc[j] = 0.f;

  for (int kt = 0; kt < LDIM; kt += 32) {
    __syncthreads();
    {
      int o = t >> 1, half = t & 1;
      const float* wp = W + (size_t)o * LDIM + kt + half * 16;
#pragma unroll
      for (int j = 0; j < 4; j++) {
        float4 vv = *(const float4*)(wp + j * 4);
        Ws[o][half * 16 + j * 4 + 0] = vv.x;
        Ws[o][half * 16 + j * 4 + 1] = vv.y;
        Ws[o][half * 16 + j * 4 + 2] = vv.z;
        Ws[o][half * 16 + j * 4 + 3] = vv.w;
      }
      int cr = t >> 3, cc = (t & 7) * 4;
      float4 cv = *(const float4*)(cb + (size_t)(kRow + cr) * LDIM + kt + cc);
      Cs[cr][cc + 0] = cv.x; Cs[cr][cc + 1] = cv.y;
      Cs[cr][cc + 2] = cv.z; Cs[cr][cc + 3] = cv.w;
    }
    __syncthreads();
#pragma unroll
    for (int lt = 0; lt < 32; lt++) {
      float cv = Cs[r][lt];
#pragma unroll
      for (int j = 0; j < 16; j++)
        acc[j] = fmaf(cv, Ws[og + 8 * j][lt], acc[j]);
    }
  }
  float* pp = P + (size_t)(kRow + r) * ODIM;
#pragma unroll
  for (int j = 0; j < 16; j++)
    pp[og + 8 * j] = acc[j] + b[og + 8 * j];
}

// ---------------- finalize: idx, loss partial, softmax(P[idx]) ----------------
__global__ __launch_bounds__(256)
void finalize_kernel(const u64* __restrict__ packed, const float* __restrict__ P,
                     float* __restrict__ out, float* __restrict__ lossAcc)
{
  __shared__ float blockLoss;
  const int t = threadIdx.x;
  if (t == 0) blockLoss = 0.f;
  const int g = t >> 5, l = t & 31;
  const int row = blockIdx.x * 8 + g;

  u64 pk = packed[row];
  int idx = (int)(u32)(pk & 0xFFFFFFFFull);
  u32 ku = (u32)(pk >> 32);
  u32 sb = (ku & 0x80000000u) ? (ku & 0x7fffffffu) : ~ku;
  float dmin = __uint_as_float(sb);

  __syncthreads();
  if (l == 0) {
    out[(size_t)NB * ODIM + 1 + row] = (float)idx;
    atomicAdd(&blockLoss, dmin);
  }

  float4 p4 = *(const float4*)(P + (size_t)idx * ODIM + l * 4);
  float m = fmaxf(fmaxf(p4.x, p4.y), fmaxf(p4.z, p4.w));
#pragma unroll
  for (int off = 1; off < 32; off <<= 1) m = fmaxf(m, __shfl_xor(m, off, 32));
  float4 ex = { __expf(p4.x - m), __expf(p4.y - m), __expf(p4.z - m), __expf(p4.w - m) };
  float s = ex.x + ex.y + ex.z + ex.w;
#pragma unroll
  for (int off = 1; off < 32; off <<= 1) s += __shfl_xor(s, off, 32);
  float inv = 1.f / s;
  float4 o4 = { ex.x * inv, ex.y * inv, ex.z * inv, ex.w * inv };
  *(float4*)(out + (size_t)row * ODIM + l * 4) = o4;

  __syncthreads();
  if (t == 0) atomicAdd(lossAcc, blockLoss);
}

__global__ void final_loss(const float* __restrict__ lossAcc, float* __restrict__ out)
{
  out[(size_t)NB * ODIM] = 1.25f * lossAcc[0] / (float)((size_t)NB * LDIM);
}

extern "C" void kernel_launch(void* const* d_in, const int* in_sizes, int n_in,
                              void* d_out, int out_size, void* d_ws, size_t ws_size,
                              hipStream_t stream)
{
  const float* x     = (const float*)d_in[0];
  const float* W_enc = (const float*)d_in[1];
  const float* b_enc = (const float*)d_in[2];
  const float* cb    = (const float*)d_in[3];
  const float* W_cls = (const float*)d_in[4];
  const float* b_cls = (const float*)d_in[5];
  float* out = (float*)d_out;

  char* ws = (char*)d_ws;
  size_t off = 0;
  float* ze      = (float*)(ws + off); off += (size_t)NB * LDIM * 4;      // 64 MiB
  float* zz      = (float*)(ws + off); off += (size_t)NB * 4;             // 64 KiB
  u64*   packed  = (u64*)  (ws + off); off += (size_t)NB * 8;             // 128 KiB
  float* lossAcc = (float*)(ws + off); off += 256;                        // loss + qcount
  float* P       = (float*)(ws + off); off += (size_t)KCB * ODIM * 4;     // 4 MiB
  u16*   zebf    = (u16*)  (ws + off); off += (size_t)NB * LDIM * 2;      // 32 MiB
  char*  cbbfR   = (ws + off);         off += (size_t)KCB * LDIM * 2;     // 16 MiB (alias: W splits)
  char*  sminR   = (ws + off);         off += (size_t)NB * NT16 * 4;      // 32 MiB

  // aliases (encoder phase): W splits live in cbbf region
  _Float16* whi = (_Float16*)cbbfR;                                  // 8 MiB
  _Float16* wlo = (_Float16*)(cbbfR + (size_t)LDIM * CIN * 2);       // 8 MiB
  u16*   cbbf = (u16*)cbbfR;
  float* smin = (float*)sminR;
  // candidate queue aliases zebf (dead after gemm); qcount in lossAcc block
  u32*   queue  = (u32*)zebf;
  u32*   qcount = (u32*)((char*)lossAcc + 64);

  hipMemsetAsync(packed, 0xFF, (size_t)NB * 8, stream);
  hipMemsetAsync(lossAcc, 0, 256, stream);

  // W_enc -> fp16 hi/lo'
  split_f16<<<(LDIM * CIN) / 2048, 256, 0, stream>>>(W_enc, whi, wlo);

  // encoder: single launch, x-split fused in-kernel (no chunking)
  enc_fused_gemm<<<dim3(LDIM / 64, NB / 128), 256, 0, stream>>>(
      x, whi, wlo, b_enc, ze, zebf);

  sqnorm_kernel<<<NB / 4, 256, 0, stream>>>(ze, zz);

  // cb -> bf16 (overwrites W splits; encoder done by stream order)
  f32_to_bf16<<<(KCB * LDIM) / 2048, 256, 0, stream>>>(cb, cbbf);

  // prune GEMM (proven 128^2 structure)
  gemm_bf16_min<<<dim3(KCB / 128, NB / 128), 256, 0, stream>>>(zebf, cbbf, smin);

  // two-phase rescore: qualify -> pair queue (in dead zebf) -> parallel exact rescore
  qualify_kernel<<<NB / 4, 256, 0, stream>>>(smin, queue, qcount);
  rescore_pairs<<<2048, 256, 0, stream>>>(queue, qcount, ze, zz, cb, packed);

  p_kernel<<<KCB / 32, 256, 0, stream>>>(cb, W_cls, b_cls, P);

  finalize_kernel<<<NB / 8, 256, 0, stream>>>(packed, P, out, lossAcc);
  final_loss<<<1, 1, 0, stream>>>(lossAcc, out);
}

// Round 10
// 1623.350 us; speedup vs baseline: 1.6416x; 1.2246x over previous
//
#include <hip/hip_runtime.h>

typedef unsigned int u32;
typedef unsigned long long u64;
typedef unsigned short u16;

// ---- problem constants ----
#define NB   16384
#define CIN  4096
#define LDIM 1024
#define KCB  8192
#define ODIM 128
#define NT16 (KCB / 16)     // 512 16-col groups per row
#define MARGIN 1e-3f        // prune margin in D space

using f32x4  = __attribute__((ext_vector_type(4))) float;
using short8 = __attribute__((ext_vector_type(8))) short;
using u16x8  = __attribute__((ext_vector_type(8))) u16;
using half8  = __attribute__((ext_vector_type(8))) _Float16;

__device__ __forceinline__ u64 packKey(float s, int idx) {
  u32 b = __float_as_uint(s);
  u32 k = (b & 0x80000000u) ? ~b : (b | 0x80000000u);
  return ((u64)k << 32) | (u32)idx;
}

__device__ __forceinline__ void gl_lds16(const void* g, void* l) {
  __builtin_amdgcn_global_load_lds((const __attribute__((address_space(1))) u32*)g,
                                   (__attribute__((address_space(3))) u32*)l, 16, 0, 0);
}

__device__ __forceinline__ u16 bf16rne(float f) {
  u32 u = __float_as_uint(f);
  u = u + 0x7fffu + ((u >> 16) & 1u);
  return (u16)(u >> 16);
}

// exact same split sequence as the old split_f16 kernel (numerics preserved)
__device__ __forceinline__ void cvt_hl(float va, _Float16& h, _Float16& lo) {
  _Float16 hh = (fabsf(va) < 6.103515625e-5f) ? (_Float16)0.f : (_Float16)va;
  h = hh;
  lo = (_Float16)((va - (float)hh) * 4096.f);
}

// ---------------- f32 -> (hi fp16, lo fp16 scaled by 2^12), 8 elems/thread ----------------
// (still used once, for W_enc)
__global__ __launch_bounds__(256)
void split_f16(const float* __restrict__ s, _Float16* __restrict__ hi,
               _Float16* __restrict__ lo)
{
  size_t i = ((size_t)blockIdx.x * 256 + threadIdx.x) * 8;
  _Float16 h8[8], l8[8];
#pragma unroll
  for (int j = 0; j < 8; j += 4) {
    float4 v = *(const float4*)(s + i + j);
    float vv[4] = { v.x, v.y, v.z, v.w };
#pragma unroll
    for (int q = 0; q < 4; q++)
      cvt_hl(vv[q], h8[j + q], l8[j + q]);
  }
  *(half8*)(hi + i) = *(half8*)h8;
  *(half8*)(lo + i) = *(half8*)l8;
}

// ---------------- f32 -> bf16 (RNE), 8 elems/thread ----------------
__global__ __launch_bounds__(256)
void f32_to_bf16(const float* __restrict__ s, u16* __restrict__ d)
{
  size_t i = ((size_t)blockIdx.x * 256 + threadIdx.x) * 8;
  float4 a = *(const float4*)(s + i);
  float4 b = *(const float4*)(s + i + 4);
  u16x8 o;
  o[0] = bf16rne(a.x); o[1] = bf16rne(a.y); o[2] = bf16rne(a.z); o[3] = bf16rne(a.w);
  o[4] = bf16rne(b.x); o[5] = bf16rne(b.y); o[6] = bf16rne(b.z); o[7] = bf16rne(b.w);
  *(u16x8*)(d + i) = o;
}

// ---------------- encoder: z = x @ W^T + b, x-split FUSED in-kernel ----------------
// (verified round 9: 635 us, MfmaUtil 30%, VALUBusy 42%) -- unchanged this round
__global__ __launch_bounds__(256, 2)
void enc_fused_gemm(const float* __restrict__ x,
                    const _Float16* __restrict__ whi, const _Float16* __restrict__ wlo,
                    const float* __restrict__ bias, float* __restrict__ ze,
                    u16* __restrict__ zebf)
{
  __shared__ _Float16 Ah[128 * 32];
  __shared__ _Float16 Al[128 * 32];
  __shared__ _Float16 Bh[64 * 32];
  __shared__ _Float16 Bl[64 * 32];

  const int t = threadIdx.x;
  const int w = t >> 6, l = t & 63;
  const int rowBase = blockIdx.y * 128;
  const int colBase = blockIdx.x * 64;
  const int mB = (w >> 1) * 64, nB = (w & 1) * 32;
  const int q = l >> 4, n16 = l & 15;

  f32x4 hh[4][2] = {}, hl[4][2] = {}, lh[4][2] = {};

  // A staging: thread handles rows {t>>2, 64+(t>>2)}, k-quarter (t&3)*8 (8 f32 = 32B contig)
  const int ar = t >> 2;            // 0..63
  const int ak = (t & 3) * 8;       // 0,8,16,24
  const float* gx0 = x + (size_t)(rowBase + ar) * CIN + ak;
  const float* gx1 = x + (size_t)(rowBase + 64 + ar) * CIN + ak;

  // W staging (async global->LDS)
  const int sr = l >> 2;            // 0..15
  const int sk = (l & 3) * 8;
  const _Float16* gBh = whi + (size_t)(colBase + 16 * w + sr) * CIN + sk;
  const _Float16* gBl = wlo + (size_t)(colBase + 16 * w + sr) * CIN + sk;
  _Float16* lBh = Bh + 16 * w * 32;
  _Float16* lBl = Bl + 16 * w * 32;

  for (int kk = 0; kk < CIN; kk += 32) {
    gl_lds16(gBh + kk, lBh);
    gl_lds16(gBl + kk, lBl);

    // x: 2 rows x 8 elems, convert, write h/l (lane addrs contiguous -> b128 floor)
    float4 v0a = *(const float4*)(gx0 + kk);
    float4 v0b = *(const float4*)(gx0 + kk + 4);
    float4 v1a = *(const float4*)(gx1 + kk);
    float4 v1b = *(const float4*)(gx1 + kk + 4);
    _Float16 h0[8], l0[8], h1[8], l1[8];
    float u0[8] = { v0a.x, v0a.y, v0a.z, v0a.w, v0b.x, v0b.y, v0b.z, v0b.w };
    float u1[8] = { v1a.x, v1a.y, v1a.z, v1a.w, v1b.x, v1b.y, v1b.z, v1b.w };
#pragma unroll
    for (int j = 0; j < 8; j++) {
      cvt_hl(u0[j], h0[j], l0[j]);
      cvt_hl(u1[j], h1[j], l1[j]);
    }
    *(half8*)&Ah[ar * 32 + ak]        = *(half8*)h0;
    *(half8*)&Al[ar * 32 + ak]        = *(half8*)l0;
    *(half8*)&Ah[(64 + ar) * 32 + ak] = *(half8*)h1;
    *(half8*)&Al[(64 + ar) * 32 + ak] = *(half8*)l1;

    __syncthreads();
    half8 ah[4], al[4], bh[2], bl[2];
#pragma unroll
    for (int ti = 0; ti < 4; ti++) {
      ah[ti] = *(const half8*)&Ah[(mB + ti * 16 + n16) * 32 + q * 8];
      al[ti] = *(const half8*)&Al[(mB + ti * 16 + n16) * 32 + q * 8];
    }
#pragma unroll
    for (int tj = 0; tj < 2; tj++) {
      bh[tj] = *(const half8*)&Bh[(nB + tj * 16 + n16) * 32 + q * 8];
      bl[tj] = *(const half8*)&Bl[(nB + tj * 16 + n16) * 32 + q * 8];
    }
    __syncthreads();   // frag reads done; next iter's writes may start during MFMA
#pragma unroll
    for (int ti = 0; ti < 4; ti++)
#pragma unroll
      for (int tj = 0; tj < 2; tj++) {
        hh[ti][tj] = __builtin_amdgcn_mfma_f32_16x16x32_f16(ah[ti], bh[tj], hh[ti][tj], 0, 0, 0);
        hl[ti][tj] = __builtin_amdgcn_mfma_f32_16x16x32_f16(ah[ti], bl[tj], hl[ti][tj], 0, 0, 0);
        lh[ti][tj] = __builtin_amdgcn_mfma_f32_16x16x32_f16(al[ti], bh[tj], lh[ti][tj], 0, 0, 0);
      }
  }

  const float S = 1.0f / 4096.0f;
#pragma unroll
  for (int tj = 0; tj < 2; tj++) {
    int c = colBase + nB + tj * 16 + n16;
    float b = bias[c];
#pragma unroll
    for (int ti = 0; ti < 4; ti++) {
      f32x4 z = hh[ti][tj] + S * (hl[ti][tj] + lh[ti][tj]);
      int m = rowBase + mB + ti * 16 + q * 4;   // D row = quad*4+reg
#pragma unroll
      for (int r = 0; r < 4; r++) {
        float zv = z[r] + b;
        ze[(size_t)(m + r) * LDIM + c] = zv;
        zebf[(size_t)(m + r) * LDIM + c] = bf16rne(zv);
      }
    }
  }
}

// ---------------- bf16 MFMA GEMM, per-(row,16colgroup) min of -2*dot ----------------
__global__ __launch_bounds__(256, 3)
void gemm_bf16_min(const u16* __restrict__ A, const u16* __restrict__ B,
                   float* __restrict__ smin)
{
  __shared__ u16 As[128 * 32];
  __shared__ u16 Bs[128 * 32];
  const int t = threadIdx.x;
  const int w = t >> 6, l = t & 63;
  const int rowBase = blockIdx.y * 128, colBase = blockIdx.x * 128;
  const int mB = (w >> 1) * 64, nB = (w & 1) * 64;
  const int q = l >> 4, n16 = l & 15;

  f32x4 acc[4][4] = {};

  const int sr = 32 * w + (l >> 2);
  const int sk = (l & 3) * 8;
  const u16* gA = A + (size_t)(rowBase + sr) * LDIM + sk;
  const u16* gB = B + (size_t)(colBase + sr) * LDIM + sk;
  u16* lA = As + 32 * w * 32;
  u16* lB = Bs + 32 * w * 32;

  for (int kk = 0; kk < LDIM; kk += 32) {
    gl_lds16(gA + kk, lA);
    gl_lds16(gA + kk + 16 * LDIM, lA + 16 * 32);
    gl_lds16(gB + kk, lB);
    gl_lds16(gB + kk + 16 * LDIM, lB + 16 * 32);
    __syncthreads();
    short8 af[4], bf[4];
#pragma unroll
    for (int ti = 0; ti < 4; ti++)
      af[ti] = *(const short8*)&As[(mB + ti * 16 + n16) * 32 + q * 8];
#pragma unroll
    for (int tj = 0; tj < 4; tj++)
      bf[tj] = *(const short8*)&Bs[(nB + tj * 16 + n16) * 32 + q * 8];
#pragma unroll
    for (int ti = 0; ti < 4; ti++)
#pragma unroll
      for (int tj = 0; tj < 4; tj++)
        acc[ti][tj] = __builtin_amdgcn_mfma_f32_16x16x32_bf16(af[ti], bf[tj], acc[ti][tj], 0, 0, 0);
    __syncthreads();
  }

  const int g0 = blockIdx.x * 8 + (w & 1) * 4;
#pragma unroll
  for (int ti = 0; ti < 4; ti++)
#pragma unroll
    for (int tj = 0; tj < 4; tj++) {
      f32x4 v = acc[ti][tj];
#pragma unroll
      for (int off = 1; off < 16; off <<= 1) {
        v.x = fmaxf(v.x, __shfl_xor(v.x, off));
        v.y = fmaxf(v.y, __shfl_xor(v.y, off));
        v.z = fmaxf(v.z, __shfl_xor(v.z, off));
        v.w = fmaxf(v.w, __shfl_xor(v.w, off));
      }
      if (n16 == 0) {
        int m = rowBase + mB + ti * 16 + q * 4;
        float* p = smin + (size_t)m * NT16 + g0 + tj;
        p[0 * NT16] = -2.f * v.x;
        p[1 * NT16] = -2.f * v.y;
        p[2 * NT16] = -2.f * v.z;
        p[3 * NT16] = -2.f * v.w;
      }
    }
}

// ---------------- dst[r] = ||src[r]||^2 (width 1024), one wave per row ----------------
__global__ __launch_bounds__(256)
void sqnorm_kernel(const float* __restrict__ src, float* __restrict__ dst)
{
  int row  = blockIdx.x * 4 + (threadIdx.x >> 6);
  int lane = threadIdx.x & 63;
  const float* p = src + (size_t)row * LDIM + lane * 4;
  float s = 0.f;
#pragma unroll
  for (int j = 0; j < 4; j++) {
    float4 v = *(const float4*)(p + j * 256);
    s += v.x * v.x + v.y * v.y + v.z * v.z + v.w * v.w;
  }
#pragma unroll
  for (int off = 32; off; off >>= 1) s += __shfl_down(s, off, 64);
  if (lane == 0) dst[row] = s;
}

// ---------------- qualify pass 1: per-group candidate histogram ----------------
// One wave per row; group id g = s*64 + lane. Counts into gcount[512].
__global__ __launch_bounds__(256)
void qualify_count(const float* __restrict__ smin, u32* __restrict__ gcount)
{
  const int t = threadIdx.x;
  const int row = blockIdx.x * 4 + (t >> 6);
  const int l = t & 63;
  const float* sm = smin + (size_t)row * NT16;

  float v[8]; float gmin = 1e30f;
#pragma unroll
  for (int s = 0; s < 8; s++) { v[s] = sm[s * 64 + l]; gmin = fminf(gmin, v[s]); }
#pragma unroll
  for (int off = 1; off < 64; off <<= 1) gmin = fminf(gmin, __shfl_xor(gmin, off));
  const float thr = gmin + MARGIN;

#pragma unroll
  for (int s = 0; s < 8; s++)
    if (v[s] <= thr) atomicAdd(&gcount[s * 64 + l], 1u);
}

// ---------------- exclusive prefix scan of 512 counts -> offsets[513], cursor ----------------
__global__ void scan_offsets(const u32* __restrict__ gcount, u32* __restrict__ offsets,
                             u32* __restrict__ cursor)
{
  __shared__ u32 s[512];
  const int i = threadIdx.x;     // 512 threads
  s[i] = gcount[i];
  __syncthreads();
  for (int d = 1; d < 512; d <<= 1) {
    u32 tv = (i >= d) ? s[i - d] : 0u;
    __syncthreads();
    s[i] += tv;
    __syncthreads();
  }
  u32 off = (i == 0) ? 0u : s[i - 1];
  offsets[i] = off;
  cursor[i]  = off;
  if (i == 511) offsets[512] = s[511];
}

// ---------------- qualify pass 2: scatter row ids into group buckets ----------------
__global__ __launch_bounds__(256)
void qualify_scatter(const float* __restrict__ smin, u32* __restrict__ queue,
                     u32* __restrict__ cursor)
{
  const int t = threadIdx.x;
  const int row = blockIdx.x * 4 + (t >> 6);
  const int l = t & 63;
  const float* sm = smin + (size_t)row * NT16;

  float v[8]; float gmin = 1e30f;
#pragma unroll
  for (int s = 0; s < 8; s++) { v[s] = sm[s * 64 + l]; gmin = fminf(gmin, v[s]); }
#pragma unroll
  for (int off = 1; off < 64; off <<= 1) gmin = fminf(gmin, __shfl_xor(gmin, off));
  const float thr = gmin + MARGIN;

#pragma unroll
  for (int s = 0; s < 8; s++)
    if (v[s] <= thr) {
      u32 pos = atomicAdd(&cursor[s * 64 + l], 1u);
      queue[pos] = (u32)row;
    }
}

// ---------------- grouped exact fp32 rescore ----------------
// Group's 16 cb columns (64 KB, contiguous) staged once in LDS; all rows in the
// bucket rescore from LDS. 4 sub-blocks per group x 4 waves: stride-16 over bucket.
// fma order per (row,col) identical to the verified rescore_pairs kernel.
__global__ __launch_bounds__(256)
void rescore_groups(const u32* __restrict__ queue, const u32* __restrict__ offsets,
                    const float* __restrict__ ze, const float* __restrict__ zz,
                    const float* __restrict__ cb, u64* __restrict__ packed)
{
  __shared__ float E[16 * 1024];   // 64 KB
  const int t = threadIdx.x;
  const int w = t >> 6, l = t & 63;
  const int g   = blockIdx.x & 511;
  const int sub = blockIdx.x >> 9;           // 0..3
  const u32 beg = offsets[g], end = offsets[g + 1];
  const int cnt = (int)(end - beg);
  if (cnt <= sub * 4) return;                // uniform exit; no work for this sub-block

  // stage 16 contiguous columns of cb: 16384 floats
  const float* src = cb + (size_t)g * (16 * LDIM);
  for (int i = t * 4; i < 16 * LDIM; i += 1024)
    *(float4*)&E[i] = *(const float4*)&src[i];
  __syncthreads();

  for (int jj = sub * 4 + w; jj < cnt; jj += 16) {
    const u32 row = queue[beg + jj];
    const float* z = ze + (size_t)row * LDIM;
    f32x4 zf[4];
#pragma unroll
    for (int j = 0; j < 4; j++)
      zf[j] = *(const f32x4*)(z + j * 256 + l * 4);
    const float zzr = zz[row];
    u64 best = ~0ull;

#pragma unroll 1
    for (int c4 = 0; c4 < 4; c4++) {
      const int colBase = g * 16 + c4 * 4;
      const float* ep = E + (size_t)(c4 * 4) * LDIM;
      f32x4 e0[4], e1[4], e2[4], e3[4];
#pragma unroll
      for (int j = 0; j < 4; j++) {
        e0[j] = *(const f32x4*)(ep + 0 * LDIM + j * 256 + l * 4);
        e1[j] = *(const f32x4*)(ep + 1 * LDIM + j * 256 + l * 4);
        e2[j] = *(const f32x4*)(ep + 2 * LDIM + j * 256 + l * 4);
        e3[j] = *(const f32x4*)(ep + 3 * LDIM + j * 256 + l * 4);
      }
      float d0 = 0.f, d1 = 0.f, d2 = 0.f, d3 = 0.f;
#pragma unroll
      for (int j = 0; j < 4; j++)
#pragma unroll
        for (int qq = 0; qq < 4; qq++) {
          float zv = zf[j][qq];
          d0 = fmaf(zv, e0[j][qq], d0);
          d1 = fmaf(zv, e1[j][qq], d1);
          d2 = fmaf(zv, e2[j][qq], d2);
          d3 = fmaf(zv, e3[j][qq], d3);
        }
#pragma unroll
      for (int off = 1; off < 64; off <<= 1) {
        d0 += __shfl_xor(d0, off);
        d1 += __shfl_xor(d1, off);
        d2 += __shfl_xor(d2, off);
        d3 += __shfl_xor(d3, off);
      }
      u64 k;
      k = packKey(zzr - 2.f * d0, colBase + 0); if (k < best) best = k;
      k = packKey(zzr - 2.f * d1, colBase + 1); if (k < best) best = k;
      k = packKey(zzr - 2.f * d2, colBase + 2); if (k < best) best = k;
      k = packKey(zzr - 2.f * d3, colBase + 3); if (k < best) best = k;
    }
    if (l == 0) atomicMin(&packed[row], best);
  }
}

// ---------------- P = cb @ W_cls^T + b_cls; block = 32 cb-rows x 128 cols ----------------
__global__ __launch_bounds__(256)
void p_kernel(const float* __restrict__ cb, const float* __restrict__ W,
              const float* __restrict__ b, float* __restrict__ P)
{
  __shared__ float Ws[128][33];
  __shared__ float Cs[32][33];
  const int t = threadIdx.x;
  const int r = t >> 3, og = t & 7;
  const int kRow = blockIdx.x * 32;

  float acc[16];
#pragma unroll
  for (int j = 0; j < 16; j++) acc[j] = 0.f;

  for (int kt = 0; kt < LDIM; kt += 32) {
    __syncthreads();
    {
      int o = t >> 1, half = t & 1;
      const float* wp = W + (size_t)o * LDIM + kt + half * 16;
#pragma unroll
      for (int j = 0; j < 4; j++) {
        float4 vv = *(const float4*)(wp + j * 4);
        Ws[o][half * 16 + j * 4 + 0] = vv.x;
        Ws[o][half * 16 + j * 4 + 1] = vv.y;
        Ws[o][half * 16 + j * 4 + 2] = vv.z;
        Ws[o][half * 16 + j * 4 + 3] = vv.w;
      }
      int cr = t >> 3, cc = (t & 7) * 4;
      float4 cv = *(const float4*)(cb + (size_t)(kRow + cr) * LDIM + kt + cc);
      Cs[cr][cc + 0] = cv.x; Cs[cr][cc + 1] = cv.y;
      Cs[cr][cc + 2] = cv.z; Cs[cr][cc + 3] = cv.w;
    }
    __syncthreads();
#pragma unroll
    for (int lt = 0; lt < 32; lt++) {
      float cv = Cs[r][lt];
#pragma unroll
      for (int j = 0; j < 16; j++)
        acc[j] = fmaf(cv, Ws[og + 8 * j][lt], acc[j]);
    }
  }
  float* pp = P + (size_t)(kRow + r) * ODIM;
#pragma unroll
  for (int j = 0; j < 16; j++)
    pp[og + 8 * j] = acc[j] + b[og + 8 * j];
}

// ---------------- finalize: idx, loss partial, softmax(P[idx]) ----------------
__global__ __launch_bounds__(256)
void finalize_kernel(const u64* __restrict__ packed, const float* __restrict__ P,
                     float* __restrict__ out, float* __restrict__ lossAcc)
{
  __shared__ float blockLoss;
  const int t = threadIdx.x;
  if (t == 0) blockLoss = 0.f;
  const int g = t >> 5, l = t & 31;
  const int row = blockIdx.x * 8 + g;

  u64 pk = packed[row];
  int idx = (int)(u32)(pk & 0xFFFFFFFFull);
  u32 ku = (u32)(pk >> 32);
  u32 sb = (ku & 0x80000000u) ? (ku & 0x7fffffffu) : ~ku;
  float dmin = __uint_as_float(sb);

  __syncthreads();
  if (l == 0) {
    out[(size_t)NB * ODIM + 1 + row] = (float)idx;
    atomicAdd(&blockLoss, dmin);
  }

  float4 p4 = *(const float4*)(P + (size_t)idx * ODIM + l * 4);
  float m = fmaxf(fmaxf(p4.x, p4.y), fmaxf(p4.z, p4.w));
#pragma unroll
  for (int off = 1; off < 32; off <<= 1) m = fmaxf(m, __shfl_xor(m, off, 32));
  float4 ex = { __expf(p4.x - m), __expf(p4.y - m), __expf(p4.z - m), __expf(p4.w - m) };
  float s = ex.x + ex.y + ex.z + ex.w;
#pragma unroll
  for (int off = 1; off < 32; off <<= 1) s += __shfl_xor(s, off, 32);
  float inv = 1.f / s;
  float4 o4 = { ex.x * inv, ex.y * inv, ex.z * inv, ex.w * inv };
  *(float4*)(out + (size_t)row * ODIM + l * 4) = o4;

  __syncthreads();
  if (t == 0) atomicAdd(lossAcc, blockLoss);
}

__global__ void final_loss(const float* __restrict__ lossAcc, float* __restrict__ out)
{
  out[(size_t)NB * ODIM] = 1.25f * lossAcc[0] / (float)((size_t)NB * LDIM);
}

extern "C" void kernel_launch(void* const* d_in, const int* in_sizes, int n_in,
                              void* d_out, int out_size, void* d_ws, size_t ws_size,
                              hipStream_t stream)
{
  const float* x     = (const float*)d_in[0];
  const float* W_enc = (const float*)d_in[1];
  const float* b_enc = (const float*)d_in[2];
  const float* cb    = (const float*)d_in[3];
  const float* W_cls = (const float*)d_in[4];
  const float* b_cls = (const float*)d_in[5];
  float* out = (float*)d_out;

  char* ws = (char*)d_ws;
  size_t off = 0;
  float* ze      = (float*)(ws + off); off += (size_t)NB * LDIM * 4;      // 64 MiB
  float* zz      = (float*)(ws + off); off += (size_t)NB * 4;             // 64 KiB
  u64*   packed  = (u64*)  (ws + off); off += (size_t)NB * 8;             // 128 KiB
  float* lossAcc = (float*)(ws + off); off += 256;                        // loss
  float* P       = (float*)(ws + off); off += (size_t)KCB * ODIM * 4;     // 4 MiB
  u16*   zebf    = (u16*)  (ws + off); off += (size_t)NB * LDIM * 2;      // 32 MiB
  char*  cbbfR   = (ws + off);         off += (size_t)KCB * LDIM * 2;     // 16 MiB (alias: W splits)
  char*  sminR   = (ws + off);         off += (size_t)NB * NT16 * 4;      // 32 MiB

  // aliases (encoder phase): W splits live in cbbf region
  _Float16* whi = (_Float16*)cbbfR;                                  // 8 MiB
  _Float16* wlo = (_Float16*)(cbbfR + (size_t)LDIM * CIN * 2);       // 8 MiB
  u16*   cbbf = (u16*)cbbfR;
  float* smin = (float*)sminR;
  // candidate queue aliases zebf (dead after gemm); capacity NB*NT16 u32 == 32 MiB exactly
  u32*   queue  = (u32*)zebf;
  // bucket control block carved from P (P written only later by p_kernel):
  u32*   gcount  = (u32*)P;            // [512]
  u32*   offsets = gcount + 512;       // [513]
  u32*   cursor  = offsets + 513;      // [512]

  hipMemsetAsync(packed, 0xFF, (size_t)NB * 8, stream);
  hipMemsetAsync(lossAcc, 0, 256, stream);
  hipMemsetAsync(gcount, 0, 512 * 4, stream);

  // W_enc -> fp16 hi/lo'
  split_f16<<<(LDIM * CIN) / 2048, 256, 0, stream>>>(W_enc, whi, wlo);

  // encoder: single launch, x-split fused in-kernel
  enc_fused_gemm<<<dim3(LDIM / 64, NB / 128), 256, 0, stream>>>(
      x, whi, wlo, b_enc, ze, zebf);

  sqnorm_kernel<<<NB / 4, 256, 0, stream>>>(ze, zz);

  // cb -> bf16 (overwrites W splits; encoder done by stream order)
  f32_to_bf16<<<(KCB * LDIM) / 2048, 256, 0, stream>>>(cb, cbbf);

  // prune GEMM (proven 128^2 structure)
  gemm_bf16_min<<<dim3(KCB / 128, NB / 128), 256, 0, stream>>>(zebf, cbbf, smin);

  // grouped rescore: count -> scan -> scatter -> LDS-staged per-group exact rescore
  qualify_count<<<NB / 4, 256, 0, stream>>>(smin, gcount);
  scan_offsets<<<1, 512, 0, stream>>>(gcount, offsets, cursor);
  qualify_scatter<<<NB / 4, 256, 0, stream>>>(smin, queue, cursor);
  rescore_groups<<<4 * 512, 256, 0, stream>>>(queue, offsets, ze, zz, cb, packed);

  p_kernel<<<KCB / 32, 256, 0, stream>>>(cb, W_cls, b_cls, P);

  finalize_kernel<<<NB / 8, 256, 0, stream>>>(packed, P, out, lossAcc);
  final_loss<<<1, 1, 0, stream>>>(lossAcc, out);
}